// Round 3
// baseline (163.516 us; speedup 1.0000x reference)
//
#include <hip/hip_runtime.h>
#include <math.h>

#define NN   65536
#define DEGC 16
#define DD   64
#define DD2  128
#define BB   1024
#define NEGC 10
#define NROWS (2 * BB + NEGC)      // 2058
#define NEDGE (NROWS * DEGC)       // 32928
#define MAXU  33024                // >= max uniques (32928), padded

// ---------------------------------------------------------------------------
// Mark + compact: unique hop-1 node list; flags[n] = position+1 in list.
// ---------------------------------------------------------------------------
__global__ __launch_bounds__(256) void mark_compact_kernel(
    const int* __restrict__ adj,
    const int* __restrict__ in1, const int* __restrict__ in2,
    const int* __restrict__ neg,
    int* __restrict__ flags, int* __restrict__ list, int* __restrict__ count) {

    int e = blockIdx.x * 256 + threadIdx.x;
    int nbr = 0;
    bool isnew = false;
    if (e < NEDGE) {
        int r = e >> 4, k = e & 15;
        int node = (r < BB) ? in1[r] : (r < 2 * BB ? in2[r - BB] : neg[r - 2 * BB]);
        nbr = adj[node * DEGC + k];
        int old = atomicCAS(&flags[nbr], 0, 1);
        isnew = (old == 0);
    }
    unsigned long long mask = __ballot(isnew);
    if (mask) {
        int lane = threadIdx.x & 63;
        int cnt = __popcll(mask);
        int leader = __ffsll((long long)mask) - 1;
        int base = 0;
        if (lane == leader) base = atomicAdd(count, cnt);
        base = __shfl(base, leader, 64);
        if (isnew) {
            int pos = base + __popcll(mask & ((1ull << lane) - 1));
            list[pos] = nbr;
            flags[nbr] = pos + 1;          // dense position for hop-2 lookup
        }
    }
}

// ---------------------------------------------------------------------------
// gather1: csum[a][lane] = sum_k feat[adj[list[a]][k]][lane]
// ---------------------------------------------------------------------------
__global__ __launch_bounds__(256) void gather1_kernel(
    const float* __restrict__ feat, const int* __restrict__ adj,
    const int* __restrict__ list, const int* __restrict__ count_p,
    float* __restrict__ csum) {

    int lane = threadIdx.x & 63;
    int wid = blockIdx.x * 4 + (threadIdx.x >> 6);
    int nw = gridDim.x * 4;
    int count = *count_p;
    for (int a = wid; a < count; a += nw) {
        int n = __builtin_amdgcn_readfirstlane(list[a]);
        const int* arow = adj + n * DEGC;
        float s = 0.f;
        #pragma unroll
        for (int k = 0; k < DEGC; ++k)
            s += feat[arow[k] * DD + lane];
        csum[a * DD + lane] = s;
    }
}

// ---------------------------------------------------------------------------
// gemv1: buf rows transform in place: csum -> h1 = tanh([feat[n] | csum] @ W1^T + b1)
// W1 in LDS as float4 tiles: q[(i4<<6)|j] = W1[j][4*i4 .. 4*i4+3].
// Concat vector via uniform-address float4 loads (HW broadcast).
// ---------------------------------------------------------------------------
__global__ __launch_bounds__(256) void gemv1_kernel(
    const float* __restrict__ feat, const float* __restrict__ W1,
    const float* __restrict__ b1, const int* __restrict__ list,
    const int* __restrict__ count_p, float* __restrict__ buf) {

    __shared__ float4 q[2048];           // 32 KB
    int tid = threadIdx.x;
    {
        int j = tid & 63, i4g = tid >> 6;
        #pragma unroll
        for (int g = 0; g < 8; ++g) {
            int i4 = i4g * 8 + g;
            q[(i4 << 6) | j] = *(const float4*)(W1 + j * DD2 + (i4 << 2));
        }
    }
    __syncthreads();

    int lane = tid & 63;
    int wid = blockIdx.x * 4 + (tid >> 6);
    int nw = gridDim.x * 4;
    int count = *count_p;
    float bias = b1[lane];

    for (int base = wid * 8; base < count; base += nw * 8) {
        int nb = min(8, count - base);
        const float* cf[8];
        const float* cs[8];
        int am[8];
        #pragma unroll
        for (int m = 0; m < 8; ++m) {
            int a = base + (m < nb ? m : nb - 1);   // clamp: no poison reads
            am[m] = a;
            int n = __builtin_amdgcn_readfirstlane(list[a]);
            cf[m] = feat + n * DD;
            cs[m] = buf + a * DD;
        }
        float acc[8];
        #pragma unroll
        for (int m = 0; m < 8; ++m) acc[m] = bias;

        #pragma unroll
        for (int i4 = 0; i4 < 16; ++i4) {           // c[0..63] = feat row
            float4 w = q[(i4 << 6) | lane];
            #pragma unroll
            for (int m = 0; m < 8; ++m) {
                float4 c = *(const float4*)(cf[m] + (i4 << 2));
                acc[m] += c.x * w.x + c.y * w.y + c.z * w.z + c.w * w.w;
            }
        }
        #pragma unroll
        for (int i4 = 0; i4 < 16; ++i4) {           // c[64..127] = csum row
            float4 w = q[((16 + i4) << 6) | lane];
            #pragma unroll
            for (int m = 0; m < 8; ++m) {
                float4 c = *(const float4*)(cs[m] + (i4 << 2));
                acc[m] += c.x * w.x + c.y * w.y + c.z * w.z + c.w * w.w;
            }
        }
        #pragma unroll
        for (int m = 0; m < 8; ++m)
            if (m < nb) buf[am[m] * DD + lane] = tanhf(acc[m]);
    }
}

// ---------------------------------------------------------------------------
// gather2: csum2[r][lane] = sum_k h1[flags[adj[node_r][k]]-1][lane]
// ---------------------------------------------------------------------------
__global__ __launch_bounds__(256) void gather2_kernel(
    const float* __restrict__ h1, const int* __restrict__ adj,
    const int* __restrict__ in1, const int* __restrict__ in2,
    const int* __restrict__ neg, const int* __restrict__ flags,
    float* __restrict__ csum2) {

    int lane = threadIdx.x & 63;
    int r = blockIdx.x * 4 + (threadIdx.x >> 6);
    if (r >= NROWS) return;
    int node = (r < BB) ? in1[r] : (r < 2 * BB ? in2[r - BB] : neg[r - 2 * BB]);
    node = __builtin_amdgcn_readfirstlane(node);
    const int* arow = adj + node * DEGC;
    float s = 0.f;
    #pragma unroll
    for (int k = 0; k < DEGC; ++k) {
        int a = flags[arow[k]] - 1;
        s += h1[a * DD + lane];
    }
    csum2[r * DD + lane] = s;
}

// ---------------------------------------------------------------------------
// gemv2 + normalize: out[r] = normalize([feat[node] | csum2[r]] @ W2^T + b2)
// W2 in LDS as float4 tiles q2[(i4<<7)|j]; lane owns outputs lane & lane+64.
// 2 rows per wave (share the W reads).
// ---------------------------------------------------------------------------
__global__ __launch_bounds__(256) void gemv2_kernel(
    const float* __restrict__ feat,
    const int* __restrict__ in1, const int* __restrict__ in2,
    const int* __restrict__ neg,
    const float* __restrict__ csum2, const float* __restrict__ W2,
    const float* __restrict__ b2, float* __restrict__ out) {

    __shared__ float4 q2[4096];          // 64 KB
    int tid = threadIdx.x;
    {
        int j = tid & 127, g0 = tid >> 7;
        #pragma unroll
        for (int g = 0; g < 16; ++g) {
            int i4 = g0 * 16 + g;
            q2[(i4 << 7) | j] = *(const float4*)(W2 + j * DD2 + (i4 << 2));
        }
    }
    __syncthreads();

    int lane = tid & 63;
    int wv = blockIdx.x * 4 + (tid >> 6);
    int r0 = wv * 2, r1 = wv * 2 + 1;
    bool a0 = r0 < NROWS, a1 = r1 < NROWS;
    if (!a0) return;                      // after barrier: safe

    int node0 = (r0 < BB) ? in1[r0] : (r0 < 2 * BB ? in2[r0 - BB] : neg[r0 - 2 * BB]);
    int node1 = a1 ? ((r1 < BB) ? in1[r1] : (r1 < 2 * BB ? in2[r1 - BB] : neg[r1 - 2 * BB])) : node0;
    node0 = __builtin_amdgcn_readfirstlane(node0);
    node1 = __builtin_amdgcn_readfirstlane(node1);
    const float* cf0 = feat + node0 * DD;
    const float* cf1 = feat + node1 * DD;
    const float* cs0 = csum2 + r0 * DD;
    const float* cs1 = csum2 + (a1 ? r1 : r0) * DD;

    float A0 = b2[lane], B0 = b2[DD + lane];
    float A1 = A0, B1 = B0;

    #pragma unroll
    for (int i4 = 0; i4 < 16; ++i4) {
        float4 wA = q2[(i4 << 7) | lane];
        float4 wB = q2[(i4 << 7) | (64 + lane)];
        float4 c0 = *(const float4*)(cf0 + (i4 << 2));
        float4 c1 = *(const float4*)(cf1 + (i4 << 2));
        A0 += c0.x * wA.x + c0.y * wA.y + c0.z * wA.z + c0.w * wA.w;
        B0 += c0.x * wB.x + c0.y * wB.y + c0.z * wB.z + c0.w * wB.w;
        A1 += c1.x * wA.x + c1.y * wA.y + c1.z * wA.z + c1.w * wA.w;
        B1 += c1.x * wB.x + c1.y * wB.y + c1.z * wB.z + c1.w * wB.w;
    }
    #pragma unroll
    for (int i4 = 0; i4 < 16; ++i4) {
        float4 wA = q2[((16 + i4) << 7) | lane];
        float4 wB = q2[((16 + i4) << 7) | (64 + lane)];
        float4 c0 = *(const float4*)(cs0 + (i4 << 2));
        float4 c1 = *(const float4*)(cs1 + (i4 << 2));
        A0 += c0.x * wA.x + c0.y * wA.y + c0.z * wA.z + c0.w * wA.w;
        B0 += c0.x * wB.x + c0.y * wB.y + c0.z * wB.z + c0.w * wB.w;
        A1 += c1.x * wA.x + c1.y * wA.y + c1.z * wA.z + c1.w * wA.w;
        B1 += c1.x * wB.x + c1.y * wB.y + c1.z * wB.z + c1.w * wB.w;
    }

    {
        float ss = A0 * A0 + B0 * B0;
        #pragma unroll
        for (int off = 32; off > 0; off >>= 1) ss += __shfl_xor(ss, off, 64);
        float inv = 1.0f / fmaxf(sqrtf(ss), 1e-12f);
        out[r0 * DD2 + lane]      = A0 * inv;
        out[r0 * DD2 + DD + lane] = B0 * inv;
    }
    if (a1) {
        float ss = A1 * A1 + B1 * B1;
        #pragma unroll
        for (int off = 32; off > 0; off >>= 1) ss += __shfl_xor(ss, off, 64);
        float inv = 1.0f / fmaxf(sqrtf(ss), 1e-12f);
        out[r1 * DD2 + lane]      = A1 * inv;
        out[r1 * DD2 + DD + lane] = B1 * inv;
    }
}

// ---------------------------------------------------------------------------
extern "C" void kernel_launch(void* const* d_in, const int* in_sizes, int n_in,
                              void* d_out, int out_size, void* d_ws, size_t ws_size,
                              hipStream_t stream) {
    const float* feat = (const float*)d_in[0];
    const int*   adj  = (const int*)d_in[1];
    const int*   in1  = (const int*)d_in[2];
    const int*   in2  = (const int*)d_in[3];
    const int*   neg  = (const int*)d_in[4];
    const float* W1   = (const float*)d_in[5];
    const float* b1   = (const float*)d_in[6];
    const float* W2   = (const float*)d_in[7];
    const float* b2   = (const float*)d_in[8];
    float* out = (float*)d_out;

    // ws layout (total ~9.4 MB)
    char* p = (char*)d_ws;
    float* buf   = (float*)p;                                  // [MAXU][64] csum1 -> h1 (in place)
    size_t off   = (size_t)MAXU * DD * sizeof(float);          // 8,454,144
    int*   flags = (int*)(p + off);      off += (size_t)NN * sizeof(int);
    int*   list  = (int*)(p + off);      off += (size_t)MAXU * sizeof(int);
    int*   count = (int*)(p + off);      off += 256;           // pad
    float* csum2 = (float*)(p + off);                          // [NROWS][64]

    size_t zbytes = (size_t)NN * sizeof(int) + (size_t)MAXU * sizeof(int) + 256;
    hipMemsetAsync(flags, 0, zbytes, stream);

    mark_compact_kernel<<<(NEDGE + 255) / 256, 256, 0, stream>>>(
        adj, in1, in2, neg, flags, list, count);
    gather1_kernel<<<1024, 256, 0, stream>>>(feat, adj, list, count, buf);
    gemv1_kernel<<<1024, 256, 0, stream>>>(feat, W1, b1, list, count, buf);
    gather2_kernel<<<(NROWS + 3) / 4, 256, 0, stream>>>(
        buf, adj, in1, in2, neg, flags, csum2);
    gemv2_kernel<<<(NROWS + 7) / 8, 256, 0, stream>>>(
        feat, in1, in2, neg, csum2, W2, b2, out);
}

// Round 4
// 134.214 us; speedup vs baseline: 1.2183x; 1.2183x over previous
//
#include <hip/hip_runtime.h>
#include <math.h>

#define NN   65536
#define DEGC 16
#define DD   64
#define DD2  128
#define BB   1024
#define NEGC 10
#define NROWS (2 * BB + NEGC)      // 2058
#define NEDGE (NROWS * DEGC)       // 32928
#define MAXE  33024                // 516 * 64

__device__ __forceinline__ float tanh_fast(float x) {
    float t = __expf(2.0f * x);
    return 1.0f - 2.0f * __builtin_amdgcn_rcpf(t + 1.0f);
}

// ---------------------------------------------------------------------------
// K1: per-edge gather. Edge e=(r,k): n_e = adj[node_r][k];
//     buf[e][lane] = sum_k2 feat[adj[n_e][k2]][lane]; nodes_e[e] = n_e.
// Wave-per-edge: adj rows via wave-uniform s_loads, feat rows coalesced 256B.
// ---------------------------------------------------------------------------
__global__ __launch_bounds__(256) void gather1_kernel(
    const float* __restrict__ feat, const int* __restrict__ adj,
    const int* __restrict__ in1, const int* __restrict__ in2,
    const int* __restrict__ neg,
    float* __restrict__ buf, int* __restrict__ nodes_e) {

    int lane = threadIdx.x & 63;
    int wid = blockIdx.x * 4 + (threadIdx.x >> 6);
    int nw = gridDim.x * 4;

    for (int e = wid; e < NEDGE; e += nw) {
        int r = e >> 4, k = e & 15;
        int node = (r < BB) ? in1[r] : (r < 2 * BB ? in2[r - BB] : neg[r - 2 * BB]);
        node = __builtin_amdgcn_readfirstlane(node);
        int n = adj[node * DEGC + k];               // uniform -> s_load
        n = __builtin_amdgcn_readfirstlane(n);
        const int* arow = adj + n * DEGC;           // uniform row
        float s = 0.f;
        #pragma unroll
        for (int k2 = 0; k2 < DEGC; ++k2)
            s += feat[arow[k2] * DD + lane];        // coalesced 256B row
        buf[e * DD + lane] = s;
        if (lane == 0) nodes_e[e] = n;
    }
}

// ---------------------------------------------------------------------------
// K2: per-edge GEMV, in place: buf[e] : csum -> h1 = tanh([feat[n_e]|csum]@W1^T + b1)
// Lane = edge (64 edges/block); 4 waves = 4 output j-splits of 16.
// Weights/bias: uniform addresses -> scalar loads (SGPR), c: per-lane float4.
// ---------------------------------------------------------------------------
__global__ __launch_bounds__(256) void gemv1_kernel(
    const float* __restrict__ feat, const float* __restrict__ W1,
    const float* __restrict__ b1, const int* __restrict__ nodes_e,
    float* __restrict__ buf) {

    int tid = threadIdx.x;
    int lane = tid & 63;
    int j0 = (tid >> 6) * 16;                       // 0,16,32,48
    int e = blockIdx.x * 64 + lane;                 // < MAXE always
    bool act = (e < NEDGE);
    int n = act ? nodes_e[e] : 0;

    float acc[16];
    #pragma unroll
    for (int t = 0; t < 16; ++t) acc[t] = b1[j0 + t];   // uniform -> s_load

    const float* frow = feat + n * DD;
    const float* crow = buf + e * DD;

    // Phase A: self features, cols 0..63 of W1 rows
    #pragma unroll
    for (int i4 = 0; i4 < 16; ++i4) {
        float4 cv = *(const float4*)(frow + i4 * 4);     // per-lane scatter, L1/L2
        #pragma unroll
        for (int t = 0; t < 16; ++t) {
            float4 wv = *(const float4*)(W1 + (j0 + t) * DD2 + i4 * 4);  // uniform -> s_load
            acc[t] += cv.x * wv.x + cv.y * wv.y + cv.z * wv.z + cv.w * wv.w;
        }
    }
    // Phase B: neighbor-sum, cols 64..127
    #pragma unroll
    for (int i4 = 0; i4 < 16; ++i4) {
        float4 cv = *(const float4*)(crow + i4 * 4);     // block-private rows
        #pragma unroll
        for (int t = 0; t < 16; ++t) {
            float4 wv = *(const float4*)(W1 + (j0 + t) * DD2 + DD + i4 * 4);
            acc[t] += cv.x * wv.x + cv.y * wv.y + cv.z * wv.z + cv.w * wv.w;
        }
    }

    __syncthreads();   // all reads of buf rows drained before in-place overwrite

    if (act) {
        float* orow = buf + e * DD + j0;
        #pragma unroll
        for (int t4 = 0; t4 < 4; ++t4) {
            float4 o;
            o.x = tanh_fast(acc[t4 * 4 + 0]);
            o.y = tanh_fast(acc[t4 * 4 + 1]);
            o.z = tanh_fast(acc[t4 * 4 + 2]);
            o.w = tanh_fast(acc[t4 * 4 + 3]);
            *(float4*)(orow + t4 * 4) = o;
        }
    }
}

// ---------------------------------------------------------------------------
// K3: csum2[r][lane] = sum_{k<16} buf[(16r+k)][lane]  (16 contiguous rows, coalesced)
// ---------------------------------------------------------------------------
__global__ __launch_bounds__(256) void sum16_kernel(
    const float* __restrict__ buf, float* __restrict__ csum2) {

    int lane = threadIdx.x & 63;
    int r = blockIdx.x * 4 + (threadIdx.x >> 6);
    if (r >= NROWS) return;
    const float* base = buf + (size_t)r * DEGC * DD;
    float s = 0.f;
    #pragma unroll
    for (int k = 0; k < DEGC; ++k)
        s += base[k * DD + lane];
    csum2[r * DD + lane] = s;
}

// ---------------------------------------------------------------------------
// K4: out[r] = normalize([feat[node_r] | csum2[r]] @ W2^T + b2)
// Wave-per-row (2 rows/wave); W2 as float4 tiles in LDS; c via broadcast float4.
// ---------------------------------------------------------------------------
__global__ __launch_bounds__(256) void gemv2_kernel(
    const float* __restrict__ feat,
    const int* __restrict__ in1, const int* __restrict__ in2,
    const int* __restrict__ neg,
    const float* __restrict__ csum2, const float* __restrict__ W2,
    const float* __restrict__ b2, float* __restrict__ out) {

    __shared__ float4 q2[4096];          // 64 KB
    int tid = threadIdx.x;
    {
        int j = tid & 127, g0 = tid >> 7;
        #pragma unroll
        for (int g = 0; g < 16; ++g) {
            int i4 = g0 * 16 + g;
            q2[(i4 << 7) | j] = *(const float4*)(W2 + j * DD2 + (i4 << 2));
        }
    }
    __syncthreads();

    int lane = tid & 63;
    int wv = blockIdx.x * 4 + (tid >> 6);
    int r0 = wv * 2, r1 = wv * 2 + 1;
    bool a0 = r0 < NROWS, a1 = r1 < NROWS;
    if (!a0) return;

    int node0 = (r0 < BB) ? in1[r0] : (r0 < 2 * BB ? in2[r0 - BB] : neg[r0 - 2 * BB]);
    int node1 = a1 ? ((r1 < BB) ? in1[r1] : (r1 < 2 * BB ? in2[r1 - BB] : neg[r1 - 2 * BB])) : node0;
    node0 = __builtin_amdgcn_readfirstlane(node0);
    node1 = __builtin_amdgcn_readfirstlane(node1);
    const float* cf0 = feat + node0 * DD;
    const float* cf1 = feat + node1 * DD;
    const float* cs0 = csum2 + r0 * DD;
    const float* cs1 = csum2 + (a1 ? r1 : r0) * DD;

    float A0 = b2[lane], B0 = b2[DD + lane];
    float A1 = A0, B1 = B0;

    #pragma unroll
    for (int i4 = 0; i4 < 16; ++i4) {
        float4 wA = q2[(i4 << 7) | lane];
        float4 wB = q2[(i4 << 7) | (64 + lane)];
        float4 c0 = *(const float4*)(cf0 + (i4 << 2));
        float4 c1 = *(const float4*)(cf1 + (i4 << 2));
        A0 += c0.x * wA.x + c0.y * wA.y + c0.z * wA.z + c0.w * wA.w;
        B0 += c0.x * wB.x + c0.y * wB.y + c0.z * wB.z + c0.w * wB.w;
        A1 += c1.x * wA.x + c1.y * wA.y + c1.z * wA.z + c1.w * wA.w;
        B1 += c1.x * wB.x + c1.y * wB.y + c1.z * wB.z + c1.w * wB.w;
    }
    #pragma unroll
    for (int i4 = 0; i4 < 16; ++i4) {
        float4 wA = q2[((16 + i4) << 7) | lane];
        float4 wB = q2[((16 + i4) << 7) | (64 + lane)];
        float4 c0 = *(const float4*)(cs0 + (i4 << 2));
        float4 c1 = *(const float4*)(cs1 + (i4 << 2));
        A0 += c0.x * wA.x + c0.y * wA.y + c0.z * wA.z + c0.w * wA.w;
        B0 += c0.x * wB.x + c0.y * wB.y + c0.z * wB.z + c0.w * wB.w;
        A1 += c1.x * wA.x + c1.y * wA.y + c1.z * wA.z + c1.w * wA.w;
        B1 += c1.x * wB.x + c1.y * wB.y + c1.z * wB.z + c1.w * wB.w;
    }

    {
        float ss = A0 * A0 + B0 * B0;
        #pragma unroll
        for (int off = 32; off > 0; off >>= 1) ss += __shfl_xor(ss, off, 64);
        float inv = 1.0f / fmaxf(sqrtf(ss), 1e-12f);
        out[r0 * DD2 + lane]      = A0 * inv;
        out[r0 * DD2 + DD + lane] = B0 * inv;
    }
    if (a1) {
        float ss = A1 * A1 + B1 * B1;
        #pragma unroll
        for (int off = 32; off > 0; off >>= 1) ss += __shfl_xor(ss, off, 64);
        float inv = 1.0f / fmaxf(sqrtf(ss), 1e-12f);
        out[r1 * DD2 + lane]      = A1 * inv;
        out[r1 * DD2 + DD + lane] = B1 * inv;
    }
}

// ---------------------------------------------------------------------------
extern "C" void kernel_launch(void* const* d_in, const int* in_sizes, int n_in,
                              void* d_out, int out_size, void* d_ws, size_t ws_size,
                              hipStream_t stream) {
    const float* feat = (const float*)d_in[0];
    const int*   adj  = (const int*)d_in[1];
    const int*   in1  = (const int*)d_in[2];
    const int*   in2  = (const int*)d_in[3];
    const int*   neg  = (const int*)d_in[4];
    const float* W1   = (const float*)d_in[5];
    const float* b1   = (const float*)d_in[6];
    const float* W2   = (const float*)d_in[7];
    const float* b2   = (const float*)d_in[8];
    float* out = (float*)d_out;

    // ws layout (~9.1 MB): buf [MAXE][64] f32 (csum -> h1 in place),
    // nodes_e [MAXE] int, csum2 [NROWS][64] f32.
    char* p = (char*)d_ws;
    float* buf     = (float*)p;
    size_t off     = (size_t)MAXE * DD * sizeof(float);      // 8,454,144
    int*   nodes_e = (int*)(p + off);   off += (size_t)MAXE * sizeof(int);
    float* csum2   = (float*)(p + off);

    gather1_kernel<<<2048, 256, 0, stream>>>(feat, adj, in1, in2, neg, buf, nodes_e);
    gemv1_kernel<<<MAXE / 64, 256, 0, stream>>>(feat, W1, b1, nodes_e, buf);
    sum16_kernel<<<(NROWS + 3) / 4, 256, 0, stream>>>(buf, csum2);
    gemv2_kernel<<<(NROWS + 7) / 8, 256, 0, stream>>>(
        feat, in1, in2, neg, csum2, W2, b2, out);
}

// Round 5
// 79.150 us; speedup vs baseline: 2.0659x; 1.6957x over previous
//
#include <hip/hip_runtime.h>
#include <math.h>

#define NN   65536
#define DEGC 16
#define DD   64
#define DD2  128
#define BB   1024
#define NEGC 10
#define NROWS (2 * BB + NEGC)      // 2058
#define NEDGE (NROWS * DEGC)       // 32928
#define MAXE  33024                // 516 * 64

__device__ __forceinline__ float tanh_fast(float x) {
    float t = __expf(2.0f * x);
    return 1.0f - 2.0f * __builtin_amdgcn_rcpf(t + 1.0f);
}

// ---------------------------------------------------------------------------
// K0: transpose W1 [64][128] -> W1T [128][64] (one-time, 32 KB)
// ---------------------------------------------------------------------------
__global__ __launch_bounds__(256) void transpose_w1_kernel(
    const float* __restrict__ W1, float* __restrict__ W1T) {
    int o = blockIdx.x * 1024 + threadIdx.x;      // 8 blocks x 4 elems
    #pragma unroll
    for (int t = 0; t < 4; ++t) {
        int idx = o + t * 256;                    // idx = i*64 + j
        int i = idx >> 6, j = idx & 63;
        W1T[idx] = W1[j * DD2 + i];
    }
}

// ---------------------------------------------------------------------------
// K1: per-edge gather. Edge e=(r,k): n_e = adj[node_r][k];
//     buf[e][lane] = sum_k2 feat[adj[n_e][k2]][lane]; nodes_e[e] = n_e.
// ---------------------------------------------------------------------------
__global__ __launch_bounds__(256) void gather1_kernel(
    const float* __restrict__ feat, const int* __restrict__ adj,
    const int* __restrict__ in1, const int* __restrict__ in2,
    const int* __restrict__ neg,
    float* __restrict__ buf, int* __restrict__ nodes_e) {

    int lane = threadIdx.x & 63;
    int wid = blockIdx.x * 4 + (threadIdx.x >> 6);
    int nw = gridDim.x * 4;

    for (int e = wid; e < NEDGE; e += nw) {
        int r = e >> 4, k = e & 15;
        int node = (r < BB) ? in1[r] : (r < 2 * BB ? in2[r - BB] : neg[r - 2 * BB]);
        node = __builtin_amdgcn_readfirstlane(node);
        int n = adj[node * DEGC + k];               // uniform -> s_load
        n = __builtin_amdgcn_readfirstlane(n);
        const int* arow = adj + n * DEGC;
        float s = 0.f;
        #pragma unroll
        for (int k2 = 0; k2 < DEGC; ++k2)
            s += feat[arow[k2] * DD + lane];        // coalesced 256B rows
        buf[e * DD + lane] = s;
        if (lane == 0) nodes_e[e] = n;
    }
}

// ---------------------------------------------------------------------------
// K2: per-edge GEMV in place: buf[e] : csum -> h1 = tanh([feat[n_e]|csum]@W1^T+b1)
// Lane j owns output j: W1 row j lives in 128 VGPRs (coalesced via W1T).
// Concat vector c is wave-uniform -> s_load broadcast; one accumulator/lane.
// ---------------------------------------------------------------------------
__global__ __launch_bounds__(256) void gemv1_kernel(
    const float* __restrict__ feat, const float* __restrict__ W1T,
    const float* __restrict__ b1, const int* __restrict__ nodes_e,
    float* __restrict__ buf) {

    int lane = threadIdx.x & 63;                    // output j
    int wid = blockIdx.x * 4 + (threadIdx.x >> 6);
    int nw = gridDim.x * 4;

    // Per-lane W row (statically indexed -> stays in VGPRs). Coalesced loads.
    float w[DD2];
    #pragma unroll
    for (int i = 0; i < DD2; ++i)
        w[i] = W1T[i * DD + lane];
    float bias = b1[lane];

    for (int e0 = wid; e0 < NEDGE; e0 += nw) {
        int e = __builtin_amdgcn_readfirstlane(e0);
        int n = __builtin_amdgcn_readfirstlane(nodes_e[e]);
        const float* frow = feat + n * DD;          // uniform -> s_load
        const float* crow = buf + e * DD;           // uniform -> s_load
        float acc = bias;
        #pragma unroll
        for (int i4 = 0; i4 < 16; ++i4) {
            float4 c = *(const float4*)(frow + i4 * 4);
            acc += c.x * w[i4 * 4 + 0] + c.y * w[i4 * 4 + 1]
                 + c.z * w[i4 * 4 + 2] + c.w * w[i4 * 4 + 3];
        }
        #pragma unroll
        for (int i4 = 0; i4 < 16; ++i4) {
            float4 c = *(const float4*)(crow + i4 * 4);
            acc += c.x * w[DD + i4 * 4 + 0] + c.y * w[DD + i4 * 4 + 1]
                 + c.z * w[DD + i4 * 4 + 2] + c.w * w[DD + i4 * 4 + 3];
        }
        // In-place: row e is exclusively owned by this wave; store depends on
        // the loads above -> ordered within the wave.
        buf[e * DD + lane] = tanh_fast(acc);
    }
}

// ---------------------------------------------------------------------------
// K3: csum2[r][lane] = sum_{k<16} buf[16r+k][lane] (contiguous, coalesced)
// ---------------------------------------------------------------------------
__global__ __launch_bounds__(256) void sum16_kernel(
    const float* __restrict__ buf, float* __restrict__ csum2) {

    int lane = threadIdx.x & 63;
    int r = blockIdx.x * 4 + (threadIdx.x >> 6);
    if (r >= NROWS) return;
    const float* base = buf + (size_t)r * DEGC * DD;
    float s = 0.f;
    #pragma unroll
    for (int k = 0; k < DEGC; ++k)
        s += base[k * DD + lane];
    csum2[r * DD + lane] = s;
}

// ---------------------------------------------------------------------------
// K4: out[r] = normalize([feat[node_r] | csum2[r]] @ W2^T + b2)
// ---------------------------------------------------------------------------
__global__ __launch_bounds__(256) void gemv2_kernel(
    const float* __restrict__ feat,
    const int* __restrict__ in1, const int* __restrict__ in2,
    const int* __restrict__ neg,
    const float* __restrict__ csum2, const float* __restrict__ W2,
    const float* __restrict__ b2, float* __restrict__ out) {

    __shared__ float4 q2[4096];          // 64 KB
    int tid = threadIdx.x;
    {
        int j = tid & 127, g0 = tid >> 7;
        #pragma unroll
        for (int g = 0; g < 16; ++g) {
            int i4 = g0 * 16 + g;
            q2[(i4 << 7) | j] = *(const float4*)(W2 + j * DD2 + (i4 << 2));
        }
    }
    __syncthreads();

    int lane = tid & 63;
    int wv = blockIdx.x * 4 + (tid >> 6);
    int r0 = wv * 2, r1 = wv * 2 + 1;
    bool a0 = r0 < NROWS, a1 = r1 < NROWS;
    if (!a0) return;

    int node0 = (r0 < BB) ? in1[r0] : (r0 < 2 * BB ? in2[r0 - BB] : neg[r0 - 2 * BB]);
    int node1 = a1 ? ((r1 < BB) ? in1[r1] : (r1 < 2 * BB ? in2[r1 - BB] : neg[r1 - 2 * BB])) : node0;
    node0 = __builtin_amdgcn_readfirstlane(node0);
    node1 = __builtin_amdgcn_readfirstlane(node1);
    const float* cf0 = feat + node0 * DD;
    const float* cf1 = feat + node1 * DD;
    const float* cs0 = csum2 + r0 * DD;
    const float* cs1 = csum2 + (a1 ? r1 : r0) * DD;

    float A0 = b2[lane], B0 = b2[DD + lane];
    float A1 = A0, B1 = B0;

    #pragma unroll
    for (int i4 = 0; i4 < 16; ++i4) {
        float4 wA = q2[(i4 << 7) | lane];
        float4 wB = q2[(i4 << 7) | (64 + lane)];
        float4 c0 = *(const float4*)(cf0 + (i4 << 2));
        float4 c1 = *(const float4*)(cf1 + (i4 << 2));
        A0 += c0.x * wA.x + c0.y * wA.y + c0.z * wA.z + c0.w * wA.w;
        B0 += c0.x * wB.x + c0.y * wB.y + c0.z * wB.z + c0.w * wB.w;
        A1 += c1.x * wA.x + c1.y * wA.y + c1.z * wA.z + c1.w * wA.w;
        B1 += c1.x * wB.x + c1.y * wB.y + c1.z * wB.z + c1.w * wB.w;
    }
    #pragma unroll
    for (int i4 = 0; i4 < 16; ++i4) {
        float4 wA = q2[((16 + i4) << 7) | lane];
        float4 wB = q2[((16 + i4) << 7) | (64 + lane)];
        float4 c0 = *(const float4*)(cs0 + (i4 << 2));
        float4 c1 = *(const float4*)(cs1 + (i4 << 2));
        A0 += c0.x * wA.x + c0.y * wA.y + c0.z * wA.z + c0.w * wA.w;
        B0 += c0.x * wB.x + c0.y * wB.y + c0.z * wB.z + c0.w * wB.w;
        A1 += c1.x * wA.x + c1.y * wA.y + c1.z * wA.z + c1.w * wA.w;
        B1 += c1.x * wB.x + c1.y * wB.y + c1.z * wB.z + c1.w * wB.w;
    }

    {
        float ss = A0 * A0 + B0 * B0;
        #pragma unroll
        for (int off = 32; off > 0; off >>= 1) ss += __shfl_xor(ss, off, 64);
        float inv = 1.0f / fmaxf(sqrtf(ss), 1e-12f);
        out[r0 * DD2 + lane]      = A0 * inv;
        out[r0 * DD2 + DD + lane] = B0 * inv;
    }
    if (a1) {
        float ss = A1 * A1 + B1 * B1;
        #pragma unroll
        for (int off = 32; off > 0; off >>= 1) ss += __shfl_xor(ss, off, 64);
        float inv = 1.0f / fmaxf(sqrtf(ss), 1e-12f);
        out[r1 * DD2 + lane]      = A1 * inv;
        out[r1 * DD2 + DD + lane] = B1 * inv;
    }
}

// ---------------------------------------------------------------------------
extern "C" void kernel_launch(void* const* d_in, const int* in_sizes, int n_in,
                              void* d_out, int out_size, void* d_ws, size_t ws_size,
                              hipStream_t stream) {
    const float* feat = (const float*)d_in[0];
    const int*   adj  = (const int*)d_in[1];
    const int*   in1  = (const int*)d_in[2];
    const int*   in2  = (const int*)d_in[3];
    const int*   neg  = (const int*)d_in[4];
    const float* W1   = (const float*)d_in[5];
    const float* b1   = (const float*)d_in[6];
    const float* W2   = (const float*)d_in[7];
    const float* b2   = (const float*)d_in[8];
    float* out = (float*)d_out;

    // ws layout (~9.2 MB)
    char* p = (char*)d_ws;
    float* buf     = (float*)p;                               // [MAXE][64]
    size_t off     = (size_t)MAXE * DD * sizeof(float);       // 8,454,144
    int*   nodes_e = (int*)(p + off);   off += (size_t)MAXE * sizeof(int);
    float* csum2   = (float*)(p + off); off += (size_t)NROWS * DD * sizeof(float);
    float* W1T     = (float*)(p + off);                       // [128][64], 32 KB

    transpose_w1_kernel<<<8, 256, 0, stream>>>(W1, W1T);
    gather1_kernel<<<2048, 256, 0, stream>>>(feat, adj, in1, in2, neg, buf, nodes_e);
    gemv1_kernel<<<768, 256, 0, stream>>>(feat, W1T, b1, nodes_e, buf);
    sum16_kernel<<<(NROWS + 3) / 4, 256, 0, stream>>>(buf, csum2);
    gemv2_kernel<<<(NROWS + 7) / 8, 256, 0, stream>>>(
        feat, in1, in2, neg, csum2, W2, b2, out);
}

// Round 6
// 52.931 us; speedup vs baseline: 3.0892x; 1.4953x over previous
//
#include <hip/hip_runtime.h>
#include <math.h>

#define NN   65536
#define DEGC 16
#define DD   64
#define DD2  128
#define BB   1024
#define NEGC 10
#define NROWS (2 * BB + NEGC)      // 2058
#define NEDGE (NROWS * DEGC)       // 32928

__device__ __forceinline__ float tanh_fast(float x) {
    float t = __expf(2.0f * x);
    return 1.0f - 2.0f * __builtin_amdgcn_rcpf(t + 1.0f);
}

__device__ __forceinline__ int node_of_row(int r, const int* __restrict__ in1,
                                           const int* __restrict__ in2,
                                           const int* __restrict__ neg) {
    return (r < BB) ? in1[r] : (r < 2 * BB ? in2[r - BB] : neg[r - 2 * BB]);
}

// ---------------------------------------------------------------------------
// K1: fused gather + GEMV1. Per edge e=(r,k), n = adj[node_r][k]:
//   h1[e] = tanh([feat[n] | sum_k2 feat[adj[n][k2]]] @ W1^T + b1)
// Block: stage W1 transposed in LDS (padded 65 -> conflict-free), each lane
// pulls its output row j=lane into 128 VGPRs. Per edge: gather csum in regs
// (coalesced), park in wave-private LDS row, read back via uniform-address
// ds_read_b128 (HW broadcast), FMA against VGPR-resident W row.
// ---------------------------------------------------------------------------
__global__ __launch_bounds__(256) void hop1_fused(
    const float* __restrict__ feat, const int* __restrict__ adj,
    const int* __restrict__ in1, const int* __restrict__ in2,
    const int* __restrict__ neg,
    const float* __restrict__ W1, const float* __restrict__ b1,
    float* __restrict__ h1) {

    __shared__ float wt[DD2 * 65];        // 33.3 KB, wt[i*65+j] = W1[j][i]
    __shared__ float4 cs4[4][16];         // 1 KB, wave-private csum rows

    int tid = threadIdx.x;
    // Stage W1 transposed: global coalesced, LDS bank = (i + j) % 32 -> clean.
    #pragma unroll
    for (int t = 0; t < (DD * DD2) / 256; ++t) {
        int lin = t * 256 + tid;          // lin = j*128 + i
        int j = lin >> 7, i = lin & 127;
        wt[i * 65 + j] = W1[lin];
    }
    __syncthreads();

    int lane = tid & 63;
    int w = tid >> 6;
    // Per-lane W row j=lane -> 128 VGPRs (ds_read addr consecutive per lane).
    float wreg[DD2];
    #pragma unroll
    for (int i = 0; i < DD2; ++i)
        wreg[i] = wt[i * 65 + lane];
    float bias = b1[lane];

    int wid = blockIdx.x * 4 + w;
    int nw = gridDim.x * 4;
    float* csrow = (float*)&cs4[w][0];

    for (int e0 = wid; e0 < NEDGE; e0 += nw) {
        int e = __builtin_amdgcn_readfirstlane(e0);
        int r = e >> 4, k = e & 15;
        int node = __builtin_amdgcn_readfirstlane(node_of_row(r, in1, in2, neg));
        int n = __builtin_amdgcn_readfirstlane(adj[node * DEGC + k]);
        const int* arow = adj + n * DEGC;           // uniform -> s_load row
        float s = 0.f;
        #pragma unroll
        for (int k2 = 0; k2 < DEGC; ++k2)
            s += feat[arow[k2] * DD + lane];        // coalesced 256B rows
        csrow[lane] = s;                            // wave-private: no barrier

        const float* frow = feat + n * DD;          // uniform -> scalar path
        float acc = bias;
        #pragma unroll
        for (int i4 = 0; i4 < 16; ++i4) {
            float4 c = *(const float4*)(frow + i4 * 4);
            acc += c.x * wreg[i4 * 4 + 0] + c.y * wreg[i4 * 4 + 1]
                 + c.z * wreg[i4 * 4 + 2] + c.w * wreg[i4 * 4 + 3];
        }
        #pragma unroll
        for (int i4 = 0; i4 < 16; ++i4) {
            float4 c = cs4[w][i4];                  // uniform addr -> broadcast
            acc += c.x * wreg[DD + i4 * 4 + 0] + c.y * wreg[DD + i4 * 4 + 1]
                 + c.z * wreg[DD + i4 * 4 + 2] + c.w * wreg[DD + i4 * 4 + 3];
        }
        h1[e * DD + lane] = tanh_fast(acc);
    }
}

// ---------------------------------------------------------------------------
// K2: fused sum16 + GEMV2 + normalize. 8 rows/block (4 waves x 2 rows).
//   out[r] = normalize([feat[node_r] | sum_k h1[16r+k]] @ W2^T + b2)
// W2 float4-tiled in 64 KB LDS; row-sums parked in 2 KB wave-private LDS.
// ---------------------------------------------------------------------------
__global__ __launch_bounds__(256) void hop2_fused(
    const float* __restrict__ feat, const float* __restrict__ h1,
    const int* __restrict__ in1, const int* __restrict__ in2,
    const int* __restrict__ neg,
    const float* __restrict__ W2, const float* __restrict__ b2,
    float* __restrict__ out) {

    __shared__ float4 q2[4096];           // 64 KB: q2[(i4<<7)|j] = W2[j][4i4..]
    __shared__ float4 cs4[8][16];         // 2 KB

    int tid = threadIdx.x;
    {
        int j = tid & 127, g0 = tid >> 7;
        #pragma unroll
        for (int g = 0; g < 16; ++g) {
            int i4 = g0 * 16 + g;
            q2[(i4 << 7) | j] = *(const float4*)(W2 + j * DD2 + (i4 << 2));
        }
    }

    int lane = tid & 63;
    int w = tid >> 6;
    int r0 = blockIdx.x * 8 + w * 2;
    int r1 = r0 + 1;
    bool a0 = r0 < NROWS, a1 = r1 < NROWS;

    // Row sums (coalesced: 16 contiguous h1 rows per output row).
    #pragma unroll
    for (int m = 0; m < 2; ++m) {
        int r = r0 + m;
        if (r < NROWS) {
            const float* base = h1 + (size_t)r * DEGC * DD;
            float s = 0.f;
            #pragma unroll
            for (int k = 0; k < DEGC; ++k)
                s += base[k * DD + lane];
            ((float*)&cs4[w * 2 + m][0])[lane] = s;
        }
    }
    __syncthreads();   // W2 staged (cs rows are wave-private anyway)

    int node0 = a0 ? node_of_row(r0, in1, in2, neg) : 0;
    int node1 = a1 ? node_of_row(r1, in1, in2, neg) : node0;
    node0 = __builtin_amdgcn_readfirstlane(node0);
    node1 = __builtin_amdgcn_readfirstlane(node1);
    const float* cf0 = feat + node0 * DD;
    const float* cf1 = feat + node1 * DD;

    float A0 = b2[lane], B0 = b2[DD + lane];
    float A1 = A0, B1 = B0;

    #pragma unroll
    for (int i4 = 0; i4 < 16; ++i4) {
        float4 wA = q2[(i4 << 7) | lane];
        float4 wB = q2[(i4 << 7) | (64 + lane)];
        float4 c0 = *(const float4*)(cf0 + (i4 << 2));
        float4 c1 = *(const float4*)(cf1 + (i4 << 2));
        A0 += c0.x * wA.x + c0.y * wA.y + c0.z * wA.z + c0.w * wA.w;
        B0 += c0.x * wB.x + c0.y * wB.y + c0.z * wB.z + c0.w * wB.w;
        A1 += c1.x * wA.x + c1.y * wA.y + c1.z * wA.z + c1.w * wA.w;
        B1 += c1.x * wB.x + c1.y * wB.y + c1.z * wB.z + c1.w * wB.w;
    }
    #pragma unroll
    for (int i4 = 0; i4 < 16; ++i4) {
        float4 wA = q2[((16 + i4) << 7) | lane];
        float4 wB = q2[((16 + i4) << 7) | (64 + lane)];
        float4 c0 = cs4[w * 2 + 0][i4];             // uniform -> broadcast
        float4 c1 = cs4[w * 2 + 1][i4];
        A0 += c0.x * wA.x + c0.y * wA.y + c0.z * wA.z + c0.w * wA.w;
        B0 += c0.x * wB.x + c0.y * wB.y + c0.z * wB.z + c0.w * wB.w;
        A1 += c1.x * wA.x + c1.y * wA.y + c1.z * wA.z + c1.w * wA.w;
        B1 += c1.x * wB.x + c1.y * wB.y + c1.z * wB.z + c1.w * wB.w;
    }

    if (a0) {
        float ss = A0 * A0 + B0 * B0;
        #pragma unroll
        for (int off = 32; off > 0; off >>= 1) ss += __shfl_xor(ss, off, 64);
        float inv = 1.0f / fmaxf(sqrtf(ss), 1e-12f);
        out[r0 * DD2 + lane]      = A0 * inv;
        out[r0 * DD2 + DD + lane] = B0 * inv;
    }
    if (a1) {
        float ss = A1 * A1 + B1 * B1;
        #pragma unroll
        for (int off = 32; off > 0; off >>= 1) ss += __shfl_xor(ss, off, 64);
        float inv = 1.0f / fmaxf(sqrtf(ss), 1e-12f);
        out[r1 * DD2 + lane]      = A1 * inv;
        out[r1 * DD2 + DD + lane] = B1 * inv;
    }
}

// ---------------------------------------------------------------------------
extern "C" void kernel_launch(void* const* d_in, const int* in_sizes, int n_in,
                              void* d_out, int out_size, void* d_ws, size_t ws_size,
                              hipStream_t stream) {
    const float* feat = (const float*)d_in[0];
    const int*   adj  = (const int*)d_in[1];
    const int*   in1  = (const int*)d_in[2];
    const int*   in2  = (const int*)d_in[3];
    const int*   neg  = (const int*)d_in[4];
    const float* W1   = (const float*)d_in[5];
    const float* b1   = (const float*)d_in[6];
    const float* W2   = (const float*)d_in[7];
    const float* b2   = (const float*)d_in[8];
    float* out = (float*)d_out;

    float* h1 = (float*)d_ws;     // [NEDGE][64] f32 = 8.43 MB

    hop1_fused<<<768, 256, 0, stream>>>(feat, adj, in1, in2, neg, W1, b1, h1);
    hop2_fused<<<(NROWS + 7) / 8, 256, 0, stream>>>(
        feat, h1, in1, in2, neg, W2, b2, out);
}